// Round 10
// baseline (70.922 us; speedup 1.0000x reference)
//
#include <hip/hip_runtime.h>

namespace {

typedef float v2f __attribute__((ext_vector_type(2)));
__device__ __forceinline__ v2f mk2(float a, float b) { v2f r; r.x = a; r.y = b; return r; }

constexpr int NB = 4;
constexpr int ND = 128;
constexpr int NH = 192;
constexpr int NW = 192;
constexpr int PLI = NH * NW;
constexpr int CD = 16;     // output planes per block; 128/16 = 8 exact
constexpr int LDSW = 194;  // 1 left pad + 192 + 1 right pad
constexpr int TENO = 6 * LDSW;      // tensor stride in floats (within one buffer)
constexpr int BUFO = 2 * 6 * LDSW;  // buffer stride in floats

__global__ __launch_bounds__(256, 2)
void edge_loss3d(const float* __restrict__ pred,
                 const float* __restrict__ targ,
                 float* __restrict__ out)
{
    const int lane = threadIdx.x & 63;
    const int wid  = threadIdx.x >> 6;
    const int d0   = blockIdx.x * CD;
    const int h0   = blockIdx.y * 4;          // block's 4 output rows h0..h0+3
    const int b    = blockIdx.z;

    __shared__ float lds[2][2][6][LDSW];      // [buf][tensor][staged row][w]
    __shared__ float wsum[4];

    // zero the w-pads of both buffers/tensors once (first read after barrier 0)
    if (threadIdx.x < 48) {
        const int bf = threadIdx.x / 24;
        const int t  = (threadIdx.x / 12) & 1;
        const int r  = (threadIdx.x % 12) / 2;
        const int s  = threadIdx.x & 1;
        lds[bf][t][r][s * (LDSW - 1)] = 0.f;
    }

    // staging role: wave stages tensor tw, staged rows rbase..rbase+2 (idx 0 <-> h0-1)
    const int tw = wid >> 1;
    const int rbase = (wid & 1) * 3;
    const float* sb = (tw ? targ : pred) + (size_t)b * ND * PLI + 3 * lane;

    // clamped row offsets; only first staged row (rbase==0) / last (rbase==3)
    // can be out of range -> wave-uniform mask factors rmA/rmB applied at write
    const int hh0 = h0 - 1 + rbase, hh1 = hh0 + 1, hh2 = hh0 + 2;
    const int ro0 = (hh0 < 0 ? 0 : (hh0 > NH - 1 ? NH - 1 : hh0)) * NW;
    const int ro1 = hh1 * NW;                 // always valid
    const int ro2 = (hh2 > NH - 1 ? NH - 1 : hh2) * NW;
    const float rmA = (rbase == 0 && h0 == 0) ? 0.f : 1.f;
    const float rmB = (rbase == 3 && h0 == NH - 4) ? 0.f : 1.f;

    // single write base + single read base; buf/tensor/row are literal offsets
    float* ldw = &lds[0][tw][rbase][1 + 3 * lane];
    const float* ldr = &lds[0][0][wid][1 + 3 * lane];

    // in-flight staged rows + rolling unscaled conv state (literal indices only)
    float g00, g01, g02, g10, g11, g12, g20, g21, g22;
    v2f   qa[2][3][3];   // [tensor][slot][0=ss 1=ts 2=st], w-pair (j0,j1)
    float qc[2][3][3];   // same, scalar j2
    v2f   accA = mk2(0.f, 0.f);
    float acc2 = 0.f;

#define PREFETCH(P) do {                                                      \
    const int o_ = (P) * PLI;                                                 \
    g00 = sb[o_ + ro0]; g01 = sb[o_ + ro0 + 1]; g02 = sb[o_ + ro0 + 2];       \
    g10 = sb[o_ + ro1]; g11 = sb[o_ + ro1 + 1]; g12 = sb[o_ + ro1 + 2];       \
    g20 = sb[o_ + ro2]; g21 = sb[o_ + ro2 + 1]; g22 = sb[o_ + ro2 + 2];       \
} while (0)

#define PREFETCH_M(P) do {                                                    \
    const int pc_ = (P) < 0 ? 0 : ((P) > ND - 1 ? ND - 1 : (P));              \
    const float pm_ = ((P) >= 0 && (P) < ND) ? 1.f : 0.f;                     \
    const int o_ = pc_ * PLI;                                                 \
    g00 = sb[o_ + ro0] * pm_; g01 = sb[o_ + ro0 + 1] * pm_; g02 = sb[o_ + ro0 + 2] * pm_; \
    g10 = sb[o_ + ro1] * pm_; g11 = sb[o_ + ro1 + 1] * pm_; g12 = sb[o_ + ro1 + 2] * pm_; \
    g20 = sb[o_ + ro2] * pm_; g21 = sb[o_ + ro2 + 1] * pm_; g22 = sb[o_ + ro2 + 2] * pm_; \
} while (0)

// h-boundary masking folded in here (off the load critical path)
#define STAGE_WRITE(BUF) do {                                                 \
    ldw[(BUF) * BUFO + 0] = g00 * rmA;                                        \
    ldw[(BUF) * BUFO + 1] = g01 * rmA;                                        \
    ldw[(BUF) * BUFO + 2] = g02 * rmA;                                        \
    ldw[(BUF) * BUFO + LDSW + 0] = g10;                                       \
    ldw[(BUF) * BUFO + LDSW + 1] = g11;                                       \
    ldw[(BUF) * BUFO + LDSW + 2] = g12;                                       \
    ldw[(BUF) * BUFO + 2 * LDSW + 0] = g20 * rmB;                             \
    ldw[(BUF) * BUFO + 2 * LDSW + 1] = g21 * rmB;                             \
    ldw[(BUF) * BUFO + 2 * LDSW + 2] = g22 * rmB;                             \
} while (0)

// one h-row pass of tensor T into slot SP (unscaled integer-weight convs)
#define ROWPASS(T, SP, RR, BUF) do {                                          \
    const float* rp_ = ldr + ((BUF) * BUFO + (T) * TENO + (RR) * LDSW);       \
    const float xm_ = rp_[-1], x0_ = rp_[0], x1_ = rp_[1], x2_ = rp_[2], xp_ = rp_[3]; \
    const v2f L_ = mk2(xm_, x0_), M_ = mk2(x0_, x1_), R_ = mk2(x1_, x2_);     \
    const v2f   sA_ = L_ + R_ + 2.f * M_;                                     \
    const float s2_ = x1_ + xp_ + 2.f * x2_;                                  \
    const v2f   tA_ = R_ - L_;                                                \
    const float t2_ = xp_ - x1_;                                              \
    if ((RR) == 0) {                                                          \
        qa[T][SP][0] = sA_; qc[T][SP][0] = s2_;   /* ss  */                   \
        qa[T][SP][1] = sA_; qc[T][SP][1] = s2_;   /* ts holds sv0 for now */  \
        qa[T][SP][2] = tA_; qc[T][SP][2] = t2_;   /* st  */                   \
    } else if ((RR) == 1) {                                                   \
        qa[T][SP][0] += 2.f * sA_; qc[T][SP][0] += 2.f * s2_;                 \
        /* h-sobel center weight = 0 -> ts unchanged */                       \
        qa[T][SP][2] += 2.f * tA_; qc[T][SP][2] += 2.f * t2_;                 \
    } else {                                                                  \
        qa[T][SP][0] += sA_; qc[T][SP][0] += s2_;                             \
        qa[T][SP][1] = sA_ - qa[T][SP][1]; qc[T][SP][1] = s2_ - qc[T][SP][1]; \
        qa[T][SP][2] += tA_; qc[T][SP][2] += t2_;                             \
    }                                                                         \
} while (0)

// phase: write staged plane into BUF, ONE barrier, prefetch next, compute
#define PHASE(SP, BUF, PN) do {                                               \
    STAGE_WRITE(BUF);                                                         \
    __syncthreads();                                                          \
    PREFETCH(PN);                                                             \
    ROWPASS(0, SP, 0, BUF); ROWPASS(0, SP, 1, BUF); ROWPASS(0, SP, 2, BUF);   \
    ROWPASS(1, SP, 0, BUF); ROWPASS(1, SP, 1, BUF); ROWPASS(1, SP, 2, BUF);   \
} while (0)

#define PHASE_M(SP, BUF, PN) do {                                             \
    STAGE_WRITE(BUF);                                                         \
    __syncthreads();                                                          \
    PREFETCH_M(PN);                                                           \
    ROWPASS(0, SP, 0, BUF); ROWPASS(0, SP, 1, BUF); ROWPASS(0, SP, 2, BUF);   \
    ROWPASS(1, SP, 0, BUF); ROWPASS(1, SP, 1, BUF); ROWPASS(1, SP, 2, BUF);   \
} while (0)

#define PHASE_L(SP, BUF) do {                                                 \
    STAGE_WRITE(BUF);                                                         \
    __syncthreads();                                                          \
    ROWPASS(0, SP, 0, BUF); ROWPASS(0, SP, 1, BUF); ROWPASS(0, SP, 2, BUF);   \
    ROWPASS(1, SP, 0, BUF); ROWPASS(1, SP, 1, BUF); ROWPASS(1, SP, 2, BUF);   \
} while (0)

// unscaled magnitude; all kernel scales folded into final invN (exact /16)
#define EDGEPK(T, SM, SC, SP, EA, E2) do {                                    \
    const v2f   gxA_ = qa[T][SM][2] + qa[T][SP][2] + 2.f * qa[T][SC][2];      \
    const float gx2_ = qc[T][SM][2] + qc[T][SP][2] + 2.f * qc[T][SC][2];      \
    const v2f   gyA_ = qa[T][SM][1] + qa[T][SP][1] + 2.f * qa[T][SC][1];      \
    const float gy2_ = qc[T][SM][1] + qc[T][SP][1] + 2.f * qc[T][SC][1];      \
    const v2f   gzA_ = qa[T][SP][0] - qa[T][SM][0];                           \
    const float gz2_ = qc[T][SP][0] - qc[T][SM][0];                           \
    const float epsu_ = 1e-8f * 256.f;  /* (16^2)*eps, exact pow2 scale */    \
    const v2f   dA_ = gxA_ * gxA_ + gyA_ * gyA_ + gzA_ * gzA_ + epsu_;        \
    const float d2_ = gx2_ * gx2_ + gy2_ * gy2_ + gz2_ * gz2_ + epsu_;        \
    EA = mk2(sqrtf(dA_.x), sqrtf(dA_.y));                                     \
    E2 = sqrtf(d2_);                                                          \
} while (0)

#define EMIT(SM, SC, SP) do {                                                 \
    v2f eA0_, eA1_; float e20_, e21_;                                         \
    EDGEPK(0, SM, SC, SP, eA0_, e20_);                                        \
    EDGEPK(1, SM, SC, SP, eA1_, e21_);                                        \
    const v2f dfA_ = eA0_ - eA1_;                                             \
    accA += mk2(fabsf(dfA_.x), fabsf(dfA_.y));                                \
    acc2 += fabsf(e20_ - e21_);                                               \
} while (0)

    // 18 phases: plane P_k = d0-1+k, slot = k%3, buf = k%2; phase k prefetches d0+k
    PREFETCH_M(d0 - 1);
    PHASE(0, 0, d0);                          // k=0
    PHASE(1, 1, d0 + 1);                      // k=1
    for (int gg = 0; gg < 2; ++gg) {          // k=2..13
        const int pp = d0 + 6 * gg;
        PHASE(2, 0, pp + 2); EMIT(0, 1, 2);
        PHASE(0, 1, pp + 3); EMIT(1, 2, 0);
        PHASE(1, 0, pp + 4); EMIT(2, 0, 1);
        PHASE(2, 1, pp + 5); EMIT(0, 1, 2);
        PHASE(0, 0, pp + 6); EMIT(1, 2, 0);
        PHASE(1, 1, pp + 7); EMIT(2, 0, 1);
    }
    PHASE(2, 0, d0 + 14);   EMIT(0, 1, 2);    // k=14
    PHASE(0, 1, d0 + 15);   EMIT(1, 2, 0);    // k=15
    PHASE_M(1, 0, d0 + 16); EMIT(2, 0, 1);    // k=16 (next plane may be OOB)
    PHASE_L(2, 1);          EMIT(0, 1, 2);    // k=17

#undef PREFETCH
#undef PREFETCH_M
#undef STAGE_WRITE
#undef ROWPASS
#undef PHASE
#undef PHASE_M
#undef PHASE_L
#undef EDGEPK
#undef EMIT

    // wave reduce -> block reduce -> one atomic per block
    float acc = accA.x + accA.y + acc2;
    #pragma unroll
    for (int off = 32; off > 0; off >>= 1)
        acc += __shfl_down(acc, off, 64);
    if (lane == 0) wsum[wid] = acc;
    __syncthreads();
    if (threadIdx.x == 0) {
        // fold the (1/16) kernel scale and the mean into one constant
        const float invN = 1.f / (16.f * (float)((long long)NB * ND * NH * NW));
        atomicAdd(out, (wsum[0] + wsum[1] + wsum[2] + wsum[3]) * invN);
    }
}

} // namespace

extern "C" void kernel_launch(void* const* d_in, const int* in_sizes, int n_in,
                              void* d_out, int out_size, void* d_ws, size_t ws_size,
                              hipStream_t stream) {
    const float* pred = (const float*)d_in[0];
    const float* targ = (const float*)d_in[1];
    float* out = (float*)d_out;
    (void)in_sizes; (void)n_in; (void)out_size; (void)d_ws; (void)ws_size;

    hipMemsetAsync(out, 0, sizeof(float), stream);

    dim3 grid(ND / CD, NH / 4, NB);   // (8, 48, 4) = 1536 blocks, 6/CU
    dim3 block(256);
    edge_loss3d<<<grid, block, 0, stream>>>(pred, targ, out);
}